// Round 2
// baseline (692.940 us; speedup 1.0000x reference)
//
#include <hip/hip_runtime.h>

#define D_DIM 128
#define HALF_D 64      // packed-bf16x2 elements per row

// ---------------- phase 0: h -> packed bf16 (RNE), float4-vectorized; zero row counts ----
// hb[i] = bf16(h[2i]) low 16 | bf16(h[2i+1]) high 16
__global__ void convert_h4(const float4* __restrict__ h4, uint2* __restrict__ hb2, int n4,
                           int* __restrict__ cnt, int N) {
    int i = blockIdx.x * blockDim.x + threadIdx.x;
    if (i < N) cnt[i] = 0;               // fold memset into this pass (runs before hist)
    if (i < n4) {
        float4 p = h4[i];
        unsigned b0 = __float_as_uint(p.x);
        unsigned b1 = __float_as_uint(p.y);
        unsigned b2 = __float_as_uint(p.z);
        unsigned b3 = __float_as_uint(p.w);
        unsigned r0 = (b0 + 0x7FFFu + ((b0 >> 16) & 1u)) >> 16;
        unsigned r1 = (b1 + 0x7FFFu + ((b1 >> 16) & 1u)) & 0xFFFF0000u;
        unsigned r2 = (b2 + 0x7FFFu + ((b2 >> 16) & 1u)) >> 16;
        unsigned r3 = (b3 + 0x7FFFu + ((b3 >> 16) & 1u)) & 0xFFFF0000u;
        hb2[i] = make_uint2(r0 | r1, r2 | r3);
    }
}

// ---------------- phase 1: per-row histogram, global atomics (L2-resident counters) -----
__global__ void row_hist(const int4* __restrict__ row4, int* __restrict__ cnt,
                         int E4, int E) {
    int i = blockIdx.x * blockDim.x + threadIdx.x;
    if (i < E4) {
        int4 r = row4[i];
        atomicAdd(&cnt[r.x], 1);
        atomicAdd(&cnt[r.y], 1);
        atomicAdd(&cnt[r.z], 1);
        atomicAdd(&cnt[r.w], 1);
    }
    if (i == 0) {
        const int* row = (const int*)row4;
        for (int e = 4 * E4; e < E; ++e) atomicAdd(&cnt[row[e]], 1);
    }
}

// ---------------- phase 2: device scan over N row counts (3 tiny kernels) ----------------
// 2a: per-1024-chunk sums
__global__ __launch_bounds__(1024) void scan_partial(const int* __restrict__ cnt,
                                                     int* __restrict__ bsum, int N) {
    __shared__ int ws_[16];
    int b = blockIdx.x, t = threadIdx.x;
    int i = b * 1024 + t;
    int v = (i < N) ? cnt[i] : 0;
    for (int d = 1; d < 64; d <<= 1) v += __shfl_xor(v, d);
    if ((t & 63) == 0) ws_[t >> 6] = v;
    __syncthreads();
    if (t == 0) {
        int s = 0;
        for (int k = 0; k < 16; ++k) s += ws_[k];
        bsum[b] = s;
    }
}

// 2b: exclusive scan of chunk sums in place (NS ~ 98, serial is fine)
__global__ void scan_block_sums(int* __restrict__ bsum, int NS) {
    if (blockIdx.x == 0 && threadIdx.x == 0) {
        int s = 0;
        for (int i = 0; i < NS; ++i) { int c = bsum[i]; bsum[i] = s; s += c; }
    }
}

// 2c: per-chunk inclusive scan + chunk base -> exclusive row offsets + cursors
__global__ __launch_bounds__(1024) void scan_final(const int* __restrict__ cnt,
                                                   const int* __restrict__ bbase,
                                                   int* __restrict__ row_off,
                                                   int* __restrict__ cursor, int N) {
    __shared__ int s[1024];
    int b = blockIdx.x, t = threadIdx.x;
    int i = b * 1024 + t;
    int v = (i < N) ? cnt[i] : 0;
    s[t] = v;
    __syncthreads();
    for (int d = 1; d < 1024; d <<= 1) {       // Hillis-Steele inclusive
        int x = (t >= d) ? s[t - d] : 0;
        __syncthreads();
        s[t] += x;
        __syncthreads();
    }
    if (i < N) {
        int excl = bbase[b] + s[t] - v;
        row_off[i] = excl;
        cursor[i]  = excl;
        if (i == N - 1) row_off[N] = excl + v;  // == E
    }
}

// ---------------- phase 3: single-pass counting-sort scatter -----------------------------
__global__ void scatter_csr(const int4* __restrict__ row4, const int4* __restrict__ col4,
                            const float4* __restrict__ val4, int* __restrict__ cursor,
                            int2* __restrict__ dst, int E4, int E) {
    int i = blockIdx.x * blockDim.x + threadIdx.x;
    if (i < E4) {
        int4   r = row4[i];
        int4   c = col4[i];
        float4 v = val4[i];
        int p0 = atomicAdd(&cursor[r.x], 1);
        int p1 = atomicAdd(&cursor[r.y], 1);
        int p2 = atomicAdd(&cursor[r.z], 1);
        int p3 = atomicAdd(&cursor[r.w], 1);
        dst[p0] = make_int2(c.x, __float_as_int(v.x));
        dst[p1] = make_int2(c.y, __float_as_int(v.y));
        dst[p2] = make_int2(c.z, __float_as_int(v.z));
        dst[p3] = make_int2(c.w, __float_as_int(v.w));
    }
    if (i == 0) {
        const int*   row = (const int*)row4;
        const int*   col = (const int*)col4;
        const float* val = (const float*)val4;
        for (int e = 4 * E4; e < E; ++e) {
            int p = atomicAdd(&cursor[row[e]], 1);
            dst[p] = make_int2(col[e], __float_as_int(val[e]));
        }
    }
}

// ---------------- phase 4: aggregation (unchanged v2) ------------------------------------
// 256-thread block = 4 waves = 4 rows (wave per row). No LDS, no __syncthreads.
// Wave split into four 16-lane groups; group g handles edge base+g, lane l loads
// uint4 = 8 dims (packed bf16x2) of that edge's source row.
__global__ __launch_bounds__(256) void aggregate_bf16_v2(
        const int* __restrict__ row_off, const int2* __restrict__ ed,
        const uint4* __restrict__ hb4, const float4* __restrict__ h04,
        float4* __restrict__ out4, int N) {
    int t = threadIdx.x & 63;
    int w = threadIdx.x >> 6;
    int r = blockIdx.x * 4 + w;
    if (r >= N) return;
    int g = t >> 4;        // edge group 0..3
    int l = t & 15;        // dim-chunk lane: dims 8l..8l+7
    int start = row_off[r];
    int end   = row_off[r + 1];
    float a0 = 0.f, a1 = 0.f, a2 = 0.f, a3 = 0.f;
    float a4 = 0.f, a5 = 0.f, a6 = 0.f, a7 = 0.f;
    #pragma unroll 4
    for (int b = start; b < end; b += 4) {
        int ei = b + g;
        int2 eg = (ei < end) ? ed[ei] : make_int2(0, 0);   // v=0 kills padding lanes
        float v = __int_as_float(eg.y);
        uint4 q = hb4[((size_t)(unsigned)eg.x << 4) + l];
        a0 = fmaf(v, __uint_as_float(q.x << 16), a0);
        a1 = fmaf(v, __uint_as_float(q.x & 0xFFFF0000u), a1);
        a2 = fmaf(v, __uint_as_float(q.y << 16), a2);
        a3 = fmaf(v, __uint_as_float(q.y & 0xFFFF0000u), a3);
        a4 = fmaf(v, __uint_as_float(q.z << 16), a4);
        a5 = fmaf(v, __uint_as_float(q.z & 0xFFFF0000u), a5);
        a6 = fmaf(v, __uint_as_float(q.w << 16), a6);
        a7 = fmaf(v, __uint_as_float(q.w & 0xFFFF0000u), a7);
    }
    // reduce across the four 16-lane groups (lanes differing in bits 4,5)
    a0 += __shfl_xor(a0, 16); a0 += __shfl_xor(a0, 32);
    a1 += __shfl_xor(a1, 16); a1 += __shfl_xor(a1, 32);
    a2 += __shfl_xor(a2, 16); a2 += __shfl_xor(a2, 32);
    a3 += __shfl_xor(a3, 16); a3 += __shfl_xor(a3, 32);
    a4 += __shfl_xor(a4, 16); a4 += __shfl_xor(a4, 32);
    a5 += __shfl_xor(a5, 16); a5 += __shfl_xor(a5, 32);
    a6 += __shfl_xor(a6, 16); a6 += __shfl_xor(a6, 32);
    a7 += __shfl_xor(a7, 16); a7 += __shfl_xor(a7, 32);
    if (t < 16) {
        size_t o = (size_t)r * 32 + 2 * l;
        float4 g0 = h04[o];
        float4 g1 = h04[o + 1];
        out4[o]     = make_float4(fmaf(0.9f, a0, 0.1f * g0.x),
                                  fmaf(0.9f, a1, 0.1f * g0.y),
                                  fmaf(0.9f, a2, 0.1f * g0.z),
                                  fmaf(0.9f, a3, 0.1f * g0.w));
        out4[o + 1] = make_float4(fmaf(0.9f, a4, 0.1f * g1.x),
                                  fmaf(0.9f, a5, 0.1f * g1.y),
                                  fmaf(0.9f, a6, 0.1f * g1.z),
                                  fmaf(0.9f, a7, 0.1f * g1.w));
    }
}

// fp32 variant (used only if ws can't fit the bf16 copy of h)
__global__ __launch_bounds__(64) void aggregate_f32(const int* __restrict__ row_off,
                                                    const int2* __restrict__ ed,
                                                    const float2* __restrict__ h2,
                                                    const float2* __restrict__ h02,
                                                    float2* __restrict__ out2) {
    __shared__ int2 lds[64];
    int r = blockIdx.x;
    int t = threadIdx.x;
    int start = row_off[r];
    int end   = row_off[r + 1];
    float ax = 0.0f, ay = 0.0f;
    for (int base = start; base < end; base += 64) {
        int n = end - base;
        if (n > 64) n = 64;
        if (t < n) lds[t] = ed[base + t];
        __syncthreads();
        for (int j = 0; j < n; ++j) {
            int c = lds[j].x;
            float v = __int_as_float(lds[j].y);
            float2 hc = h2[(size_t)c * HALF_D + t];
            ax = fmaf(v, hc.x, ax);
            ay = fmaf(v, hc.y, ay);
        }
        __syncthreads();
    }
    float2 g = h02[(size_t)r * HALF_D + t];
    float2 o;
    o.x = fmaf(0.9f, ax, 0.1f * g.x);
    o.y = fmaf(0.9f, ay, 0.1f * g.y);
    out2[(size_t)r * HALF_D + t] = o;
}

// ---------------- fallback: direct atomic scatter ----------------
__global__ void init_out(const float* __restrict__ h0, float* __restrict__ out, int n) {
    int i = blockIdx.x * blockDim.x + threadIdx.x;
    if (i < n) out[i] = 0.1f * h0[i];
}

__global__ void scatter_atomic(const int* __restrict__ row, const int* __restrict__ col,
                               const float* __restrict__ val, const float* __restrict__ h,
                               float* __restrict__ out, int E) {
    long idx = (long)blockIdx.x * blockDim.x + threadIdx.x;
    int e = (int)(idx >> 6);
    if (e >= E) return;
    int t = (int)(idx & 63);
    int r = row[e], c = col[e];
    float v = 0.9f * val[e];
    atomicAdd(&out[(size_t)r * D_DIM + 2 * t],     v * h[(size_t)c * D_DIM + 2 * t]);
    atomicAdd(&out[(size_t)r * D_DIM + 2 * t + 1], v * h[(size_t)c * D_DIM + 2 * t + 1]);
}

extern "C" void kernel_launch(void* const* d_in, const int* in_sizes, int n_in,
                              void* d_out, int out_size, void* d_ws, size_t ws_size,
                              hipStream_t stream) {
    const int*   edge_row = (const int*)d_in[0];
    const int*   edge_col = (const int*)d_in[1];
    const float* edge_val = (const float*)d_in[2];
    const float* h        = (const float*)d_in[3];
    const float* h0       = (const float*)d_in[4];
    float*       out      = (float*)d_out;

    const int E  = in_sizes[0];
    const int N  = in_sizes[3] / D_DIM;
    const int NS = (N + 1023) / 1024;          // scan chunks

    auto align16 = [](size_t x) { return (x + 15) & ~(size_t)15; };
    size_t cnt_off     = 0;
    size_t rowoff_off  = align16(cnt_off + (size_t)N * 4);
    size_t cursor_off  = align16(rowoff_off + (size_t)(N + 1) * 4);
    size_t bsum_off    = align16(cursor_off + (size_t)N * 4);
    size_t sorted_off  = align16(bsum_off + (size_t)NS * 4);
    size_t hbf_off     = align16(sorted_off + (size_t)E * 8);
    size_t ws_f32      = hbf_off;                            // without bf16 h copy
    size_t ws_bf16     = hbf_off + (size_t)N * HALF_D * 4;   // with bf16 h copy

    char* ws = (char*)d_ws;
    bool ok   = (ws_size >= ws_f32);
    bool okbf = ok && (ws_size >= ws_bf16);
    if (ok) {
        int*  cnt     = (int*)(ws + cnt_off);
        int*  row_off = (int*)(ws + rowoff_off);
        int*  cursor  = (int*)(ws + cursor_off);
        int*  bsum    = (int*)(ws + bsum_off);
        int2* sorted  = (int2*)(ws + sorted_off);
        unsigned int* hbf = (unsigned int*)(ws + hbf_off);

        const int E4 = E >> 2;
        if (okbf) {
            int n4 = N * 32;                   // float4 elements in h
            convert_h4<<<(n4 + 255) / 256, 256, 0, stream>>>((const float4*)h,
                                                             (uint2*)hbf, n4, cnt, N);
        } else {
            hipMemsetAsync(cnt, 0, (size_t)N * 4, stream);
        }
        row_hist<<<(E4 + 255) / 256, 256, 0, stream>>>((const int4*)edge_row, cnt, E4, E);
        scan_partial<<<NS, 1024, 0, stream>>>(cnt, bsum, N);
        scan_block_sums<<<1, 64, 0, stream>>>(bsum, NS);
        scan_final<<<NS, 1024, 0, stream>>>(cnt, bsum, row_off, cursor, N);
        scatter_csr<<<(E4 + 255) / 256, 256, 0, stream>>>((const int4*)edge_row,
                                                          (const int4*)edge_col,
                                                          (const float4*)edge_val,
                                                          cursor, sorted, E4, E);
        if (okbf) {
            aggregate_bf16_v2<<<(N + 3) / 4, 256, 0, stream>>>(row_off, sorted,
                                                 (const uint4*)hbf,
                                                 (const float4*)h0, (float4*)out, N);
        } else {
            aggregate_f32<<<N, 64, 0, stream>>>(row_off, sorted,
                                                (const float2*)h, (const float2*)h0,
                                                (float2*)out);
        }
    } else {
        int nd = N * D_DIM;
        init_out<<<(nd + 255) / 256, 256, 0, stream>>>(h0, out, nd);
        long total_threads = (long)E * 64;
        scatter_atomic<<<(int)((total_threads + 255) / 256), 256, 0, stream>>>(
            edge_row, edge_col, edge_val, h, out, E);
    }
}

// Round 3
// 419.040 us; speedup vs baseline: 1.6536x; 1.6536x over previous
//
#include <hip/hip_runtime.h>

#define D_DIM 128
#define HALF_D 64      // packed-bf16x2 elements per row
#define RPB 64         // rows per bucket
#define RPB_SHIFT 6
#define MAXNB 2048     // LDS histogram bound (NB = 1563 here)
#define CHUNK 2560     // max edges per bucket handled by LDS sort (mean 2048, sigma 45)
#define KSTAGE 10      // CHUNK / 256 threads

// ---------------- phase 0: h -> packed bf16 (RNE), float4-vectorized; zero bucket counts
// hb[i] = bf16(h[2i]) low 16 | bf16(h[2i+1]) high 16
__global__ void convert_h4(const float4* __restrict__ h4, uint2* __restrict__ hb2, int n4,
                           int* __restrict__ counts, int NB) {
    int i = blockIdx.x * blockDim.x + threadIdx.x;
    if (i < NB) counts[i] = 0;          // fold memset into this pass (runs before hist)
    if (i < n4) {
        float4 p = h4[i];
        unsigned b0 = __float_as_uint(p.x);
        unsigned b1 = __float_as_uint(p.y);
        unsigned b2 = __float_as_uint(p.z);
        unsigned b3 = __float_as_uint(p.w);
        unsigned r0 = (b0 + 0x7FFFu + ((b0 >> 16) & 1u)) >> 16;
        unsigned r1 = (b1 + 0x7FFFu + ((b1 >> 16) & 1u)) & 0xFFFF0000u;
        unsigned r2 = (b2 + 0x7FFFu + ((b2 >> 16) & 1u)) >> 16;
        unsigned r3 = (b3 + 0x7FFFu + ((b3 >> 16) & 1u)) & 0xFFFF0000u;
        hb2[i] = make_uint2(r0 | r1, r2 | r3);
    }
}

// ---------------- phase 1: coarse bucket histogram (LDS-accumulated) ----------------
__global__ void bucket_hist(const int* __restrict__ row, int* __restrict__ counts,
                            int E, int NB) {
    __shared__ int h[MAXNB];
    for (int i = threadIdx.x; i < NB; i += blockDim.x) h[i] = 0;
    __syncthreads();
    int chunk = (E + gridDim.x - 1) / gridDim.x;
    int lo = blockIdx.x * chunk;
    int hi = min(E, lo + chunk);
    for (int e = lo + threadIdx.x; e < hi; e += blockDim.x)
        atomicAdd(&h[row[e] >> RPB_SHIFT], 1);
    __syncthreads();
    for (int i = threadIdx.x; i < NB; i += blockDim.x)
        if (h[i]) atomicAdd(&counts[i], h[i]);
}

// ---------------- phase 2: scan bucket counts (one block) ----------------
__global__ __launch_bounds__(256) void bucket_scan(const int* __restrict__ counts,
                                                   int* __restrict__ off,
                                                   int* __restrict__ cursor, int NB) {
    __shared__ int tot[256];
    int t = threadIdx.x;
    int vals[8];
    int cnts[8];
    int s = 0;
    for (int k = 0; k < 8; ++k) {
        int i = t * 8 + k;
        int c = (i < NB) ? counts[i] : 0;
        cnts[k] = c;
        s += c;
        vals[k] = s;                 // inclusive within thread
    }
    tot[t] = s;
    __syncthreads();
    for (int d = 1; d < 256; d <<= 1) {   // Hillis-Steele inclusive
        int v = (t >= d) ? tot[t - d] : 0;
        __syncthreads();
        tot[t] += v;
        __syncthreads();
    }
    int base = (t > 0) ? tot[t - 1] : 0;
    for (int k = 0; k < 8; ++k) {
        int i = t * 8 + k;
        if (i < NB) {
            int incl = base + vals[k];
            off[i + 1] = incl;
            cursor[i] = incl - cnts[k];   // exclusive prefix = bucket start
        }
    }
    if (t == 0) off[0] = 0;
}

// ---------------- phase 3: bucketed scatter, block-local reservation ----------------
// Block-local reservation keeps each block's writes to a bucket CONTIGUOUS —
// this is what prevents the 8x write amplification a per-edge global cursor causes.
__global__ __launch_bounds__(1024) void bucket_scatter(const int* __restrict__ row,
        const int* __restrict__ col, const float* __restrict__ val,
        int* __restrict__ cursor, int2* __restrict__ sorted, int E, int NB) {
    __shared__ int h[MAXNB];
    for (int i = threadIdx.x; i < NB; i += blockDim.x) h[i] = 0;
    __syncthreads();
    int chunk = (E + gridDim.x - 1) / gridDim.x;
    int lo = blockIdx.x * chunk;
    int hi = min(E, lo + chunk);
    for (int e = lo + threadIdx.x; e < hi; e += blockDim.x)
        atomicAdd(&h[row[e] >> RPB_SHIFT], 1);
    __syncthreads();
    for (int i = threadIdx.x; i < NB; i += blockDim.x) {
        int c = h[i];
        h[i] = c ? atomicAdd(&cursor[i], c) : 0;   // h[i] becomes local write cursor
    }
    __syncthreads();
    for (int e = lo + threadIdx.x; e < hi; e += blockDim.x) {
        int r = row[e];
        int b = r >> RPB_SHIFT;
        int p = atomicAdd(&h[b], 1);
        // pack: low 20 bits = col (N < 2^20), bits 20..25 = local row
        sorted[p] = make_int2(col[e] | ((r & (RPB - 1)) << 20), __float_as_int(val[e]));
    }
}

// ---------------- phase 4: FUSED within-bucket row sort (LDS) + aggregation ----------
// One block per bucket (64 rows). Stage bucket edges into registers (coalesced),
// LDS histogram+scan over 64 local rows, scatter into LDS buf (row-sorted),
// then v2-style aggregation: wave w handles rows w, w+4, ...; wave split into
// four 16-lane groups, group g = edge base+g, lane l loads uint4 = dims 8l..8l+7.
__global__ __launch_bounds__(256) void sort_aggregate(
        const int* __restrict__ off, const int2* __restrict__ ed,
        const uint4* __restrict__ hb4, const float4* __restrict__ h04,
        float4* __restrict__ out4, int N) {
    __shared__ int2 buf[CHUNK];
    __shared__ int cnt[RPB];
    __shared__ int segs[RPB];
    __shared__ int cur[RPB];
    int b = blockIdx.x;
    int tid = threadIdx.x;
    int t = tid & 63;
    int w = tid >> 6;
    int g = t >> 4;        // edge group 0..3
    int l = t & 15;        // dim-chunk lane: dims 8l..8l+7
    int start = off[b], end = off[b + 1];
    int nE = end - start;
    int row0 = b << RPB_SHIFT;

    if (nE <= CHUNK) {
        // ---- stage + histogram ----
        if (tid < RPB) cnt[tid] = 0;
        __syncthreads();
        int ex[KSTAGE], ey[KSTAGE];
        #pragma unroll
        for (int k = 0; k < KSTAGE; ++k) {
            int idx = start + tid + k * 256;
            if (idx < end) {
                int2 e = ed[idx];
                ex[k] = e.x; ey[k] = e.y;
                atomicAdd(&cnt[(e.x >> 20) & (RPB - 1)], 1);
            } else {
                ex[k] = -1;
            }
        }
        __syncthreads();
        // ---- exclusive scan of 64 counters (wave 0) ----
        if (tid < RPB) {
            int v = cnt[tid];
            int inc = v;
            #pragma unroll
            for (int d = 1; d < RPB; d <<= 1) {
                int x = __shfl_up(inc, d);
                if (tid >= d) inc += x;
            }
            segs[tid] = inc - v;   // segment start (0-based in buf)
            cur[tid]  = inc - v;   // scatter cursor
        }
        __syncthreads();
        // ---- scatter into LDS, row-sorted ----
        #pragma unroll
        for (int k = 0; k < KSTAGE; ++k) {
            if (ex[k] != -1) {
                int p = atomicAdd(&cur[(ex[k] >> 20) & (RPB - 1)], 1);
                buf[p] = make_int2(ex[k] & 0xFFFFF, ey[k]);
            }
        }
        __syncthreads();           // after this, cur[lr] == segment end
        // ---- aggregate: wave w owns rows w, w+4, ..., 8 fp32 accums per lane ----
        for (int lr = w; lr < RPB; lr += 4) {
            int r = row0 + lr;
            if (r >= N) break;
            int s0 = segs[lr], s1 = cur[lr];
            float a0 = 0.f, a1 = 0.f, a2 = 0.f, a3 = 0.f;
            float a4 = 0.f, a5 = 0.f, a6 = 0.f, a7 = 0.f;
            #pragma unroll 4
            for (int base = s0; base < s1; base += 4) {
                int ei = base + g;
                int2 e = (ei < s1) ? buf[ei] : make_int2(0, 0);  // v=0 kills pad lanes
                float v = __int_as_float(e.y);
                uint4 q = hb4[((size_t)(unsigned)e.x << 4) + l];
                a0 = fmaf(v, __uint_as_float(q.x << 16), a0);
                a1 = fmaf(v, __uint_as_float(q.x & 0xFFFF0000u), a1);
                a2 = fmaf(v, __uint_as_float(q.y << 16), a2);
                a3 = fmaf(v, __uint_as_float(q.y & 0xFFFF0000u), a3);
                a4 = fmaf(v, __uint_as_float(q.z << 16), a4);
                a5 = fmaf(v, __uint_as_float(q.z & 0xFFFF0000u), a5);
                a6 = fmaf(v, __uint_as_float(q.w << 16), a6);
                a7 = fmaf(v, __uint_as_float(q.w & 0xFFFF0000u), a7);
            }
            a0 += __shfl_xor(a0, 16); a0 += __shfl_xor(a0, 32);
            a1 += __shfl_xor(a1, 16); a1 += __shfl_xor(a1, 32);
            a2 += __shfl_xor(a2, 16); a2 += __shfl_xor(a2, 32);
            a3 += __shfl_xor(a3, 16); a3 += __shfl_xor(a3, 32);
            a4 += __shfl_xor(a4, 16); a4 += __shfl_xor(a4, 32);
            a5 += __shfl_xor(a5, 16); a5 += __shfl_xor(a5, 32);
            a6 += __shfl_xor(a6, 16); a6 += __shfl_xor(a6, 32);
            a7 += __shfl_xor(a7, 16); a7 += __shfl_xor(a7, 32);
            if (t < 16) {
                size_t o = (size_t)r * 32 + 2 * l;
                float4 g0 = h04[o];
                float4 g1 = h04[o + 1];
                out4[o]     = make_float4(fmaf(0.9f, a0, 0.1f * g0.x),
                                          fmaf(0.9f, a1, 0.1f * g0.y),
                                          fmaf(0.9f, a2, 0.1f * g0.z),
                                          fmaf(0.9f, a3, 0.1f * g0.w));
                out4[o + 1] = make_float4(fmaf(0.9f, a4, 0.1f * g1.x),
                                          fmaf(0.9f, a5, 0.1f * g1.y),
                                          fmaf(0.9f, a6, 0.1f * g1.z),
                                          fmaf(0.9f, a7, 0.1f * g1.w));
            }
        }
    } else {
        // ---- fallback (statistically never for this input): full scan per row ----
        for (int lr = w; lr < RPB; lr += 4) {
            int r = row0 + lr;
            if (r >= N) break;
            float a0 = 0.f, a1 = 0.f, a2 = 0.f, a3 = 0.f;
            float a4 = 0.f, a5 = 0.f, a6 = 0.f, a7 = 0.f;
            for (int base = start; base < end; base += 4) {
                int ei = base + g;
                int2 e = (ei < end) ? ed[ei] : make_int2(0, 0);
                float v = (((e.x >> 20) & (RPB - 1)) == lr) ? __int_as_float(e.y) : 0.f;
                uint4 q = hb4[((size_t)(unsigned)(e.x & 0xFFFFF) << 4) + l];
                a0 = fmaf(v, __uint_as_float(q.x << 16), a0);
                a1 = fmaf(v, __uint_as_float(q.x & 0xFFFF0000u), a1);
                a2 = fmaf(v, __uint_as_float(q.y << 16), a2);
                a3 = fmaf(v, __uint_as_float(q.y & 0xFFFF0000u), a3);
                a4 = fmaf(v, __uint_as_float(q.z << 16), a4);
                a5 = fmaf(v, __uint_as_float(q.z & 0xFFFF0000u), a5);
                a6 = fmaf(v, __uint_as_float(q.w << 16), a6);
                a7 = fmaf(v, __uint_as_float(q.w & 0xFFFF0000u), a7);
            }
            a0 += __shfl_xor(a0, 16); a0 += __shfl_xor(a0, 32);
            a1 += __shfl_xor(a1, 16); a1 += __shfl_xor(a1, 32);
            a2 += __shfl_xor(a2, 16); a2 += __shfl_xor(a2, 32);
            a3 += __shfl_xor(a3, 16); a3 += __shfl_xor(a3, 32);
            a4 += __shfl_xor(a4, 16); a4 += __shfl_xor(a4, 32);
            a5 += __shfl_xor(a5, 16); a5 += __shfl_xor(a5, 32);
            a6 += __shfl_xor(a6, 16); a6 += __shfl_xor(a6, 32);
            a7 += __shfl_xor(a7, 16); a7 += __shfl_xor(a7, 32);
            if (t < 16) {
                size_t o = (size_t)r * 32 + 2 * l;
                float4 g0 = h04[o];
                float4 g1 = h04[o + 1];
                out4[o]     = make_float4(fmaf(0.9f, a0, 0.1f * g0.x),
                                          fmaf(0.9f, a1, 0.1f * g0.y),
                                          fmaf(0.9f, a2, 0.1f * g0.z),
                                          fmaf(0.9f, a3, 0.1f * g0.w));
                out4[o + 1] = make_float4(fmaf(0.9f, a4, 0.1f * g1.x),
                                          fmaf(0.9f, a5, 0.1f * g1.y),
                                          fmaf(0.9f, a6, 0.1f * g1.z),
                                          fmaf(0.9f, a7, 0.1f * g1.w));
            }
        }
    }
}

// ---------------- fallback: direct atomic scatter ----------------
__global__ void init_out(const float* __restrict__ h0, float* __restrict__ out, int n) {
    int i = blockIdx.x * blockDim.x + threadIdx.x;
    if (i < n) out[i] = 0.1f * h0[i];
}

__global__ void scatter_atomic(const int* __restrict__ row, const int* __restrict__ col,
                               const float* __restrict__ val, const float* __restrict__ h,
                               float* __restrict__ out, int E) {
    long idx = (long)blockIdx.x * blockDim.x + threadIdx.x;
    int e = (int)(idx >> 6);
    if (e >= E) return;
    int t = (int)(idx & 63);
    int r = row[e], c = col[e];
    float v = 0.9f * val[e];
    atomicAdd(&out[(size_t)r * D_DIM + 2 * t],     v * h[(size_t)c * D_DIM + 2 * t]);
    atomicAdd(&out[(size_t)r * D_DIM + 2 * t + 1], v * h[(size_t)c * D_DIM + 2 * t + 1]);
}

extern "C" void kernel_launch(void* const* d_in, const int* in_sizes, int n_in,
                              void* d_out, int out_size, void* d_ws, size_t ws_size,
                              hipStream_t stream) {
    const int*   edge_row = (const int*)d_in[0];
    const int*   edge_col = (const int*)d_in[1];
    const float* edge_val = (const float*)d_in[2];
    const float* h        = (const float*)d_in[3];
    const float* h0       = (const float*)d_in[4];
    float*       out      = (float*)d_out;

    const int E  = in_sizes[0];
    const int N  = in_sizes[3] / D_DIM;
    const int NB = (N + RPB - 1) / RPB;

    auto align16 = [](size_t x) { return (x + 15) & ~(size_t)15; };
    size_t counts_off  = 0;
    size_t off_off     = align16(counts_off + (size_t)NB * 4);
    size_t cursor_off  = align16(off_off + (size_t)(NB + 1) * 4);
    size_t sorted_off  = align16(cursor_off + (size_t)NB * 4);
    size_t hbf_off     = align16(sorted_off + (size_t)E * 8);
    size_t ws_need     = hbf_off + (size_t)N * HALF_D * 4;   // + bf16 h copy

    char* ws = (char*)d_ws;
    bool ok = (ws_size >= ws_need) && (NB <= MAXNB) && (N < (1 << 20));
    if (ok) {
        int*  counts  = (int*)(ws + counts_off);
        int*  offs    = (int*)(ws + off_off);
        int*  cursor  = (int*)(ws + cursor_off);
        int2* sorted  = (int2*)(ws + sorted_off);
        unsigned int* hbf = (unsigned int*)(ws + hbf_off);

        int n4 = N * (D_DIM / 4);          // float4 elements in h
        convert_h4<<<(n4 + 255) / 256, 256, 0, stream>>>((const float4*)h,
                                                         (uint2*)hbf, n4, counts, NB);
        bucket_hist<<<256, 256, 0, stream>>>(edge_row, counts, E, NB);
        bucket_scan<<<1, 256, 0, stream>>>(counts, offs, cursor, NB);
        bucket_scatter<<<256, 1024, 0, stream>>>(edge_row, edge_col, edge_val,
                                                 cursor, sorted, E, NB);
        sort_aggregate<<<NB, 256, 0, stream>>>(offs, sorted, (const uint4*)hbf,
                                               (const float4*)h0, (float4*)out, N);
    } else {
        int nd = N * D_DIM;
        init_out<<<(nd + 255) / 256, 256, 0, stream>>>(h0, out, nd);
        long total_threads = (long)E * 64;
        scatter_atomic<<<(int)((total_threads + 255) / 256), 256, 0, stream>>>(
            edge_row, edge_col, edge_val, h, out, E);
    }
}